// Round 13
// baseline (384.125 us; speedup 1.0000x reference)
//
#include <hip/hip_runtime.h>
#include <hip/hip_bf16.h>
#include <stdint.h>

typedef __bf16 bf16;
typedef __bf16 bf16x4 __attribute__((ext_vector_type(4)));
typedef __bf16 bf16x8 __attribute__((ext_vector_type(8)));
typedef float  f32x4  __attribute__((ext_vector_type(4)));

#define L_TOT 1024
#define B_TOT 64
#define C_TOT 1024            // ENC2 (= K)
#define D_TOT 512             // DEC
#define E_TOT 512
#define M_TOT (L_TOT * B_TOT) // 65536
#define W_LD  (C_TOT + D_TOT) // 1536

#define NT 256                // 4 waves: 2m x 2n, wave tile 64x64, block 128x128

__device__ __forceinline__ bf16x8 cvt8(f32x4 a, f32x4 b) {
  bf16x8 o;
  o[0]=(bf16)a[0]; o[1]=(bf16)a[1]; o[2]=(bf16)a[2]; o[3]=(bf16)a[3];
  o[4]=(bf16)b[0]; o[5]=(bf16)b[1]; o[6]=(bf16)b[2]; o[7]=(bf16)b[3];
  return o;
}

__device__ __forceinline__ float tanh_fast(float x) {
  float e = __expf(2.0f * x);
  return 1.0f - __fdividef(2.0f, e + 1.0f);
}

// ---- prep: Wa_e (fp32, row stride 1536) -> bf16 [512][1024] in ws ----
__global__ void convert_we_kernel(const float* __restrict__ Wattn,
                                  bf16* __restrict__ Wb) {
  const int e = blockIdx.x;
  const int t = threadIdx.x;
  const float4 v = ((const float4*)(Wattn + (size_t)e * W_LD))[t];
  bf16x4 o;
  o[0]=(bf16)v.x; o[1]=(bf16)v.y; o[2]=(bf16)v.z; o[3]=(bf16)v.w;
  ((bf16x4*)(Wb + (size_t)e * C_TOT))[t] = o;
}

// ---- prep: sb[b][e] = sum_d s[b,d] * Wa_s[e,d] ----
__global__ void sb_kernel(const float* __restrict__ s,
                          const float* __restrict__ Wattn,
                          float* __restrict__ sb) {
  const int e = blockIdx.x;
  const int b = threadIdx.x;
  const float4* sr = (const float4*)(s + (size_t)b * D_TOT);
  const float4* wr = (const float4*)(Wattn + (size_t)e * W_LD + C_TOT);
  float acc = 0.f;
#pragma unroll 4
  for (int i = 0; i < D_TOT / 4; ++i) {
    float4 a = sr[i], w = wr[i];
    acc += a.x * w.x; acc += a.y * w.y; acc += a.z * w.z; acc += a.w * w.w;
  }
  sb[(size_t)b * E_TOT + e] = acc;
}

// ---- main GEMM + fused tanh/dot epilogue: BARRIER-FREE K-loop, PURE C ----
// Like R10/R11 (direct global->register fragment loads, no LDS, no barriers,
// 8 desynchronized waves/CU) but with ZERO inline asm in the K-loop: plain C
// vector loads; the compiler owns all s_waitcnt placement, so nothing can
// dangle and no manual ledger can be wrong.  2-deep C pipeline: set(t+1)
// loads issue before compute(t) consumes set(t) -> one-k-step latency cover,
// plus cross-wave TLP (m114).  A-redundancy dedups in L1 / same-XCD L2
// (R8-proven swizzle).  Numerics identical to R8 (same fragment mapping).
__global__ __launch_bounds__(NT, 2)
void gemm_tanh_dot_kernel(const float* __restrict__ A,
                          const bf16*  __restrict__ Wb,
                          const float* __restrict__ sb,
                          const float* __restrict__ Wv,
                          float* __restrict__ logitsQ) {
  __shared__ float red[512];        // epilogue only

  const int tid  = threadIdx.x;
  const int lane = tid & 63;
  const int wid  = tid >> 6;        // 0..3
  const int wm   = wid >> 1;        // 0..1 m-half
  const int wn   = wid & 1;         // 0..1 e-half
  const int fr   = lane & 15;
  const int fg   = lane >> 4;

  const int blk = blockIdx.x;
  const int gx  = (blk & 7) | ((blk >> 5) << 3);  // 512 m-tiles
  const int gy  = (blk >> 3) & 3;                 // 4 e-quarters, same-XCD sibs
  const int m0  = gx << 7;
  const int e0  = gy << 7;

  // fragment base pointers (per lane); A frag = A[m0+wm*64+am*16+fr][fg*8+..]
  const float* baseA[4];
  const bf16*  baseB[4];
#pragma unroll
  for (int am = 0; am < 4; ++am)
    baseA[am] = A + (size_t)(m0 + (wm << 6) + (am << 4) + fr) * C_TOT + (fg << 3);
#pragma unroll
  for (int bn = 0; bn < 4; ++bn)
    baseB[bn] = Wb + (size_t)(e0 + (wn << 6) + (bn << 4) + fr) * C_TOT + (fg << 3);

  f32x4 acc[4][4];
#pragma unroll
  for (int i = 0; i < 4; ++i)
#pragma unroll
    for (int j = 0; j < 4; ++j)
      acc[i][j] = (f32x4){0.f, 0.f, 0.f, 0.f};

  f32x4  aS0[8], aS1[8];
  bf16x8 bS0[4], bS1[4];

  auto loadset = [&](f32x4* av, bf16x8* bv, int t) {
    const int ko = t << 5;
#pragma unroll
    for (int am = 0; am < 4; ++am) {
      av[2 * am]     = *(const f32x4*)(baseA[am] + ko);
      av[2 * am + 1] = *(const f32x4*)(baseA[am] + ko + 4);
    }
#pragma unroll
    for (int bn = 0; bn < 4; ++bn)
      bv[bn] = *(const bf16x8*)(baseB[bn] + ko);
  };

  auto computeset = [&](const f32x4* av, const bf16x8* bv) {
    bf16x8 fa[4];
#pragma unroll
    for (int am = 0; am < 4; ++am)
      fa[am] = cvt8(av[2 * am], av[2 * am + 1]);
    __builtin_amdgcn_s_setprio(1);
#pragma unroll
    for (int am = 0; am < 4; ++am)
#pragma unroll
      for (int bn = 0; bn < 4; ++bn)
        acc[am][bn] = __builtin_amdgcn_mfma_f32_16x16x32_bf16(
            fa[am], bv[bn], acc[am][bn], 0, 0, 0);
    __builtin_amdgcn_s_setprio(0);
  };

  // ---- barrier-free pipelined K-loop: 32 k-steps of 32 ----
  loadset(aS0, bS0, 0);
#pragma unroll 1
  for (int kp = 0; kp < 16; ++kp) {
    const int t = kp << 1;
    loadset(aS1, bS1, t + 1);
    computeset(aS0, bS0);
    if (kp < 15) loadset(aS0, bS0, t + 2);
    computeset(aS1, bS1);
  }

  // ---- fused epilogue: +sb, tanh, *Wv, reduce over this block's 128 e ----
  float wv[4];
#pragma unroll
  for (int bn = 0; bn < 4; ++bn)
    wv[bn] = Wv[e0 + (wn << 6) + (bn << 4) + fr];

#pragma unroll
  for (int am = 0; am < 4; ++am) {
#pragma unroll
    for (int j = 0; j < 4; ++j) {
      const int mloc = (wm << 6) + (am << 4) + (fg << 2) + j;  // 0..127
      const int bi = mloc & 63;                                // m = l*64+b
      const float* sbr = sb + (size_t)bi * E_TOT + e0 + (wn << 6) + fr;
      float c = 0.f;
#pragma unroll
      for (int bn = 0; bn < 4; ++bn)
        c += tanh_fast(acc[am][bn][j] + sbr[bn << 4]) * wv[bn];
      c += __shfl_xor(c, 1, 64);
      c += __shfl_xor(c, 2, 64);
      c += __shfl_xor(c, 4, 64);
      c += __shfl_xor(c, 8, 64);
      if (fr == 0) red[(wn << 7) + mloc] = c;
    }
  }
  __syncthreads();
  if (tid < 128)
    logitsQ[((size_t)gy << 16) + m0 + tid] = red[tid] + red[128 + tid];
}

// ---- softmax over l per b; logits[m] = sum of 4 quarters; out[b][l] ----
__global__ __launch_bounds__(256)
void softmax_kernel(const float* __restrict__ lQ, float* __restrict__ out) {
  const int b = blockIdx.x;
  const int t = threadIdx.x;
  const int lane = t & 63, w = t >> 6;
  __shared__ float sm[8];
  float x[4];
  float mx = -3.4e38f;
#pragma unroll
  for (int i = 0; i < 4; ++i) {
    const int m = (t + (i << 8)) * 64 + b;
    x[i] = (lQ[m] + lQ[(1 << 16) + m]) + (lQ[(2 << 16) + m] + lQ[(3 << 16) + m]);
    mx = fmaxf(mx, x[i]);
  }
#pragma unroll
  for (int off = 1; off < 64; off <<= 1)
    mx = fmaxf(mx, __shfl_xor(mx, off, 64));
  if (lane == 0) sm[w] = mx;
  __syncthreads();
  mx = fmaxf(fmaxf(sm[0], sm[1]), fmaxf(sm[2], sm[3]));
  float ex[4], ssum = 0.f;
#pragma unroll
  for (int i = 0; i < 4; ++i) { ex[i] = __expf(x[i] - mx); ssum += ex[i]; }
#pragma unroll
  for (int off = 1; off < 64; off <<= 1)
    ssum += __shfl_xor(ssum, off, 64);
  if (lane == 0) sm[4 + w] = ssum;
  __syncthreads();
  const float inv = 1.0f / (sm[4] + sm[5] + sm[6] + sm[7]);
#pragma unroll
  for (int i = 0; i < 4; ++i)
    out[(size_t)b * 1024 + t + (i << 8)] = ex[i] * inv;
}

extern "C" void kernel_launch(void* const* d_in, const int* in_sizes, int n_in,
                              void* d_out, int out_size, void* d_ws, size_t ws_size,
                              hipStream_t stream) {
  const float* enc = (const float*)d_in[0];  // (1024, 64, 1024) fp32
  const float* s   = (const float*)d_in[1];  // (1, 64, 512)     fp32
  const float* Wat = (const float*)d_in[2];  // (512, 1536)      fp32
  const float* Wv  = (const float*)d_in[3];  // (1, 512)         fp32
  float* out = (float*)d_out;                // (64, 1024)       fp32

  char* ws = (char*)d_ws;
  bf16*  Wb      = (bf16*)ws;                                 // 1 MB
  float* sb      = (float*)(ws + (1u << 20));                 // 128 KB
  float* logitsQ = (float*)(ws + (1u << 20) + (128u << 10));  // 1 MB

  convert_we_kernel<<<E_TOT, 256, 0, stream>>>(Wat, Wb);
  sb_kernel<<<E_TOT, 64, 0, stream>>>(s, Wat, sb);
  gemm_tanh_dot_kernel<<<512 * 4, NT, 0, stream>>>(enc, Wb, sb, Wv, logitsQ);
  softmax_kernel<<<B_TOT, 256, 0, stream>>>(logitsQ, out);
}

// Round 14
// 151.071 us; speedup vs baseline: 2.5427x; 2.5427x over previous
//
#include <hip/hip_runtime.h>
#include <hip/hip_bf16.h>
#include <stdint.h>

typedef __bf16 bf16;
typedef __bf16 bf16x4 __attribute__((ext_vector_type(4)));
typedef __bf16 bf16x8 __attribute__((ext_vector_type(8)));
typedef float  f32x4  __attribute__((ext_vector_type(4)));

#define L_TOT 1024
#define B_TOT 64
#define C_TOT 1024            // ENC2 (= K)
#define D_TOT 512             // DEC
#define E_TOT 512
#define M_TOT (L_TOT * B_TOT) // 65536
#define W_LD  (C_TOT + D_TOT) // 1536

#define BM 128
#define BN 256
#define BK 64
#define NT 512
#define NKT (C_TOT / BK)      // 16

__device__ __forceinline__ void gload_lds16(const void* g, void* l) {
  __builtin_amdgcn_global_load_lds(
      (const __attribute__((address_space(1))) unsigned int*)(uintptr_t)g,
      (__attribute__((address_space(3))) unsigned int*)(uintptr_t)l,
      16, 0, 0);
}

__device__ __forceinline__ bf16x8 cvt8(f32x4 a, f32x4 b) {
  bf16x8 o;
  o[0]=(bf16)a[0]; o[1]=(bf16)a[1]; o[2]=(bf16)a[2]; o[3]=(bf16)a[3];
  o[4]=(bf16)b[0]; o[5]=(bf16)b[1]; o[6]=(bf16)b[2]; o[7]=(bf16)b[3];
  return o;
}

__device__ __forceinline__ float tanh_fast(float x) {
  // exact identity tanh(x) = 1 - 2/(e^{2x}+1); overflow-graceful at both ends.
  float e = __expf(2.0f * x);
  return 1.0f - __fdividef(2.0f, e + 1.0f);
}

// ---- prep: Wa_e (fp32, row stride 1536) -> bf16 [512][1024] in ws ----
__global__ void convert_we_kernel(const float* __restrict__ Wattn,
                                  bf16* __restrict__ Wb) {
  const int e = blockIdx.x;   // 512
  const int t = threadIdx.x;  // 256
  const float4 v = ((const float4*)(Wattn + (size_t)e * W_LD))[t];
  bf16x4 o;
  o[0]=(bf16)v.x; o[1]=(bf16)v.y; o[2]=(bf16)v.z; o[3]=(bf16)v.w;
  ((bf16x4*)(Wb + (size_t)e * C_TOT))[t] = o;
}

// ---- prep: sb[b][e] = sum_d s[b,d] * Wa_s[e,d] ----
__global__ void sb_kernel(const float* __restrict__ s,
                          const float* __restrict__ Wattn,
                          float* __restrict__ sb) {
  const int e = blockIdx.x;   // 512
  const int b = threadIdx.x;  // 64
  const float4* sr = (const float4*)(s + (size_t)b * D_TOT);
  const float4* wr = (const float4*)(Wattn + (size_t)e * W_LD + C_TOT);
  float acc = 0.f;
#pragma unroll 4
  for (int i = 0; i < D_TOT / 4; ++i) {
    float4 a = sr[i], w = wr[i];
    acc += a.x * w.x; acc += a.y * w.y; acc += a.z * w.z; acc += a.w * w.w;
  }
  sb[(size_t)b * E_TOT + e] = acc;
}

// ---- main GEMM + fused tanh/dot epilogue ----
// BM=128 x BN=256, BK=64.  8 waves = 2m x 4n, wave tile 64x64.
// A: reg-staged fp32->bf16, pair-row LDS (R1 0-conflict scheme), 2 bufs.
// B: global_load_lds, R1 scheme, 3 bufs.  LDS 128KB.
// Per tile: issue B(t+2),A(t+2); vmcnt(8) [drains t+1 exactly]; write A(t+1);
// 2 phases {8 ds_read; lgkmcnt(0); 16 MFMA}; raw barrier (no vmem drain).
// Validated champion (bench 151.06 us, absmax 6.1e-5) — R13 reverts to it
// after the barrier-free family proved L1-throughput-bound (R12) and
// instruction-level variants faulted (R10/R11).
__global__ __launch_bounds__(NT, 2)
void gemm_tanh_dot_kernel(const float* __restrict__ A,
                          const bf16*  __restrict__ Wb,
                          const float* __restrict__ sb,
                          const float* __restrict__ Wv,
                          float* __restrict__ logitsH) {
  __shared__ __align__(16) char smem[2 * 16384 + 3 * 32768];  // 128 KB
  char* const Aa0 = smem;
  char* const Aa1 = smem + 16384;
  char* const Bq0 = smem + 32768;
  char* const Bq1 = smem + 65536;
  char* const Bq2 = smem + 98304;

  const int tid  = threadIdx.x;
  const int lane = tid & 63;
  const int wid  = tid >> 6;
  const int wm   = wid >> 2;        // 0..1
  const int wn   = wid & 3;         // 0..3
  const int fr   = lane & 15;
  const int fg   = lane >> 4;

  const int blk = blockIdx.x;
  const int gx  = (blk & 7) | ((blk >> 4) << 3);  // pairs (b,b+8): same gx, same XCD
  const int gy  = (blk >> 3) & 1;
  const int m0  = gx << 7;
  const int e0  = gy << 8;

  // A staging: thread -> row=tid>>2 (0..127), 16 floats at k16=(tid&3)*16
  const float* gA = A + (size_t)(m0 + (tid >> 2)) * C_TOT + ((tid & 3) << 4);
  const int p_a  = tid >> 3;
  const int rb_a = (tid >> 2) & 1;
  const int hf_a = (tid >> 1) & 1;
  const int qb_a = (tid & 1) << 1;
  const int awo0 = hf_a * 8192 + p_a * 128 + ((((rb_a << 2) | qb_a))     ^ (p_a & 7)) * 16;
  const int awo1 = hf_a * 8192 + p_a * 128 + ((((rb_a << 2) | (qb_a+1))) ^ (p_a & 7)) * 16;

  // B staging (R1-verified): linear dest, inverse-swizzled src
  const int b_s = (tid & 7) ^ ((tid >> 3) & 7);
  const int b_e = ((tid >> 3) << 1) + (b_s >> 2);
  const bf16* gB = Wb + (size_t)(e0 + b_e) * C_TOT + ((b_s & 3) << 3);
  const int bdst = tid << 4;

  // fragment read offsets
  const int sx  = (((((fr & 1) << 2) | fg)) ^ (fr >> 1)) << 4;
  const int aro = ((wm << 5) + (fr >> 1)) * 128 + sx;   // + am*1024 + kk*8192
  const int bro = ((wn << 5) + (fr >> 1)) * 128 + sx;   // + bn*1024 + kk*16384

  f32x4 acc[4][4];
#pragma unroll
  for (int i = 0; i < 4; ++i)
#pragma unroll
    for (int j = 0; j < 4; ++j)
      acc[i][j] = (f32x4){0.f, 0.f, 0.f, 0.f};

  f32x4 av00, av01, av02, av03, av10, av11, av12, av13;

  auto stageB = [&](char* Bp, int t) {
    const bf16* sp = gB + (t << 6);
    gload_lds16(sp,           Bp + bdst);
    gload_lds16(sp + 131072,  Bp + bdst + 8192);
    gload_lds16(sp + 32,          Bp + bdst + 16384);
    gload_lds16(sp + 32 + 131072, Bp + bdst + 24576);
  };

#define LOADA(p, t)                                                            \
  { const float* ap_ = gA + ((t) << 6);                                        \
    asm volatile("global_load_dwordx4 %0, %1, off"           : "=v"(av##p##0) : "v"(ap_) : "memory"); \
    asm volatile("global_load_dwordx4 %0, %1, off offset:16" : "=v"(av##p##1) : "v"(ap_) : "memory"); \
    asm volatile("global_load_dwordx4 %0, %1, off offset:32" : "=v"(av##p##2) : "v"(ap_) : "memory"); \
    asm volatile("global_load_dwordx4 %0, %1, off offset:48" : "=v"(av##p##3) : "v"(ap_) : "memory"); }

#define WRITEA(Ap, p)                                                          \
  { *(bf16x8*)((Ap) + awo0) = cvt8(av##p##0, av##p##1);                        \
    *(bf16x8*)((Ap) + awo1) = cvt8(av##p##2, av##p##3); }

  auto phase = [&](int kk, const char* Ap, const char* Bp) {
    bf16x8 af[4], bf[4];
    const char* Ab = Ap + kk * 8192  + aro;
    const char* Bb = Bp + kk * 16384 + bro;
#pragma unroll
    for (int am = 0; am < 4; ++am) af[am] = *(const bf16x8*)(Ab + am * 1024);
#pragma unroll
    for (int bn = 0; bn < 4; ++bn) bf[bn] = *(const bf16x8*)(Bb + bn * 1024);
    asm volatile("s_waitcnt lgkmcnt(0)" ::: "memory");
    __builtin_amdgcn_sched_barrier(0);
    __builtin_amdgcn_s_setprio(1);
#pragma unroll
    for (int am = 0; am < 4; ++am)
#pragma unroll
      for (int bn = 0; bn < 4; ++bn)
        acc[am][bn] = __builtin_amdgcn_mfma_f32_16x16x32_bf16(
            af[am], bf[bn], acc[am][bn], 0, 0, 0);
    __builtin_amdgcn_s_setprio(0);
    __builtin_amdgcn_sched_barrier(0);
  };

#define BARRIER()                                                              \
  asm volatile("s_waitcnt lgkmcnt(0)" ::: "memory");                           \
  __builtin_amdgcn_s_barrier();                                                \
  __builtin_amdgcn_sched_barrier(0);

  // ---- prologue: Q = [B0x4, A0x4, B1x4, A1x4] -> drain 8 -> [B1, A1]
  stageB(Bq0, 0);
  LOADA(0, 0);
  stageB(Bq1, 1);
  LOADA(1, 1);
  asm volatile("s_waitcnt vmcnt(8)" ::: "memory");
  __builtin_amdgcn_sched_barrier(0);
  WRITEA(Aa0, 0);
  BARRIER();                       // tile 0 ready

  char* B0 = Bq0; char* B1 = Bq1; char* B2 = Bq2;

#pragma unroll 1
  for (int kp = 0; kp < 7; ++kp) {
    const int t = kp << 1;
    // ---- tile t (even): cur A=Aa0,B=B0; stage B(t+2)->B2, A(t+2)->av0 ----
    stageB(B2, t + 2);
    LOADA(0, t + 2);
    asm volatile("s_waitcnt vmcnt(8)" ::: "memory");   // drains B(t+1),A(t+1)
    __builtin_amdgcn_sched_barrier(0);
    WRITEA(Aa1, 1);                                    // A(t+1) -> a1
    phase(0, Aa0, B0);
    phase(1, Aa0, B0);
    BARRIER();
    // ---- tile t+1 (odd): cur A=Aa1,B=B1; stage B(t+3)->B0, A(t+3)->av1 ----
    stageB(B0, t + 3);
    LOADA(1, t + 3);
    asm volatile("s_waitcnt vmcnt(8)" ::: "memory");   // drains B(t+2),A(t+2)
    __builtin_amdgcn_sched_barrier(0);
    WRITEA(Aa0, 0);                                    // A(t+2) -> a0
    phase(0, Aa1, B1);
    phase(1, Aa1, B1);
    BARRIER();
    // rotate: (B0,B1,B2) <- (B2,B0,B1)
    char* tmp = B2; B2 = B1; B1 = B0; B0 = tmp;
  }

  // ---- tile 14: cur A=Aa0, B=B0(=b[2]); write A(15); no new issues ----
  asm volatile("s_waitcnt vmcnt(0)" ::: "memory");     // tail drain (A15,B15)
  __builtin_amdgcn_sched_barrier(0);
  WRITEA(Aa1, 1);
  phase(0, Aa0, B0);
  phase(1, Aa0, B0);
  BARRIER();
  // ---- tile 15: cur A=Aa1, B=B1(=b[0]) ----
  phase(0, Aa1, B1);
  phase(1, Aa1, B1);

  // ---- fused epilogue: +sb, tanh, *Wv, reduce over this block's 256 e ----
  float wv[4];
#pragma unroll
  for (int bn = 0; bn < 4; ++bn)
    wv[bn] = Wv[e0 + (wn << 6) + (bn << 4) + fr];

  float* red = (float*)smem;  // [4 wn][128 m] in Aa0 region (tile15 used Aa1/B1)
#pragma unroll
  for (int am = 0; am < 4; ++am) {
#pragma unroll
    for (int j = 0; j < 4; ++j) {
      const int mloc = (wm << 6) + (am << 4) + (fg << 2) + j;  // 0..127
      const int bi = mloc & 63;                                // m = l*64+b
      const float* sbr = sb + (size_t)bi * E_TOT + e0 + (wn << 6) + fr;
      float c = 0.f;
#pragma unroll
      for (int bn = 0; bn < 4; ++bn)
        c += tanh_fast(acc[am][bn][j] + sbr[bn << 4]) * wv[bn];
      c += __shfl_xor(c, 1, 64);
      c += __shfl_xor(c, 2, 64);
      c += __shfl_xor(c, 4, 64);
      c += __shfl_xor(c, 8, 64);
      if (fr == 0) red[(wn << 7) + mloc] = c;
    }
  }
  __syncthreads();
  if (tid < BM) {
    float v = red[tid] + red[128 + tid] + red[256 + tid] + red[384 + tid];
    logitsH[(size_t)gy * M_TOT + m0 + tid] = v;
  }
#undef LOADA
#undef WRITEA
#undef BARRIER
}

// ---- softmax over l per b; logits[m] = lH0[m]+lH1[m], m = l*64+b ----
__global__ __launch_bounds__(256)
void softmax_kernel(const float* __restrict__ lH, float* __restrict__ out) {
  const int b = blockIdx.x;
  const int t = threadIdx.x;
  const int lane = t & 63, w = t >> 6;
  __shared__ float sm[8];
  float x[4];
  float mx = -3.4e38f;
#pragma unroll
  for (int i = 0; i < 4; ++i) {
    const int m = (t + (i << 8)) * 64 + b;
    x[i] = lH[m] + lH[M_TOT + m];
    mx = fmaxf(mx, x[i]);
  }
#pragma unroll
  for (int off = 1; off < 64; off <<= 1)
    mx = fmaxf(mx, __shfl_xor(mx, off, 64));
  if (lane == 0) sm[w] = mx;
  __syncthreads();
  mx = fmaxf(fmaxf(sm[0], sm[1]), fmaxf(sm[2], sm[3]));
  float ex[4], ssum = 0.f;
#pragma unroll
  for (int i = 0; i < 4; ++i) { ex[i] = __expf(x[i] - mx); ssum += ex[i]; }
#pragma unroll
  for (int off = 1; off < 64; off <<= 1)
    ssum += __shfl_xor(ssum, off, 64);
  if (lane == 0) sm[4 + w] = ssum;
  __syncthreads();
  const float inv = 1.0f / (sm[4] + sm[5] + sm[6] + sm[7]);
#pragma unroll
  for (int i = 0; i < 4; ++i)
    out[(size_t)b * 1024 + t + (i << 8)] = ex[i] * inv;
}

extern "C" void kernel_launch(void* const* d_in, const int* in_sizes, int n_in,
                              void* d_out, int out_size, void* d_ws, size_t ws_size,
                              hipStream_t stream) {
  const float* enc = (const float*)d_in[0];  // (1024, 64, 1024) fp32
  const float* s   = (const float*)d_in[1];  // (1, 64, 512)     fp32
  const float* Wat = (const float*)d_in[2];  // (512, 1536)      fp32
  const float* Wv  = (const float*)d_in[3];  // (1, 512)         fp32
  float* out = (float*)d_out;                // (64, 1024)       fp32

  char* ws = (char*)d_ws;
  bf16*  Wb      = (bf16*)ws;                                 // 1 MB
  float* sb      = (float*)(ws + (1u << 20));                 // 128 KB
  float* logitsH = (float*)(ws + (1u << 20) + (128u << 10));  // 512 KB (2 halves)

  convert_we_kernel<<<E_TOT, 256, 0, stream>>>(Wat, Wb);
  sb_kernel<<<E_TOT, 64, 0, stream>>>(s, Wat, sb);
  gemm_tanh_dot_kernel<<<(M_TOT / BM) * 2, NT, 0, stream>>>(enc, Wb, sb, Wv, logitsH);
  softmax_kernel<<<B_TOT, 256, 0, stream>>>(logitsH, out);
}